// Round 17
// baseline (124.575 us; speedup 1.0000x reference)
//
#include <hip/hip_runtime.h>
#include <stdint.h>

#define NCLS   15
#define NTH    18
#define BATCH  16
#define NANCH  49104
#define KTOP   1000
#define NWORDS 16   // 16*64 = 1024 >= 1000
#define NBIN   32768
#define BSHIFT 15
#define CAND   2048

__device__ __forceinline__ float sigmoidf(float x) {
    return 1.0f / (1.0f + expf(-x));
}

__device__ __forceinline__ void levelOf(int i, int& lvl, int& h, int& s, int& pos) {
    if (i < 36864)      { lvl = 0; h = 192; s = 8;   pos = i; }
    else if (i < 46080) { lvl = 1; h = 96;  s = 16;  pos = i - 36864; }
    else if (i < 48384) { lvl = 2; h = 48;  s = 32;  pos = i - 46080; }
    else if (i < 48960) { lvl = 3; h = 24;  s = 64;  pos = i - 48384; }
    else                { lvl = 4; h = 12;  s = 128; pos = i - 48960; }
}

__device__ __forceinline__ unsigned long long shfl_u64(unsigned long long v, int src) {
    int lo = __shfl((int)(unsigned int)(v & 0xFFFFFFFFull), src);
    int hi = __shfl((int)(unsigned int)(v >> 32), src);
    return ((unsigned long long)(unsigned int)hi << 32) | (unsigned long long)(unsigned int)lo;
}

__device__ __forceinline__ void atomicOr64Shared(unsigned long long* p, unsigned long long v) {
    unsigned int* q = (unsigned int*)p;
    unsigned int lo = (unsigned int)v;
    unsigned int hi = (unsigned int)(v >> 32);
    if (lo) atomicOr(q, lo);
    if (hi) atomicOr(q + 1, hi);
}

// ---- Kernel 1: pure-stream scores + exact class argmax --------------------------
__global__ __launch_bounds__(256) void k_scores(
    const float* __restrict__ c0, const float* __restrict__ c1,
    const float* __restrict__ c2, const float* __restrict__ c3,
    const float* __restrict__ c4,
    float* __restrict__ scores, unsigned char* __restrict__ classes)
{
    int g4 = blockIdx.x * 256 + threadIdx.x;
    if (g4 >= BATCH * NANCH / 4) return;
    int g = g4 * 4;
    int b = g / NANCH;
    int i = g - b * NANCH;          // multiple of 4; level boundaries are too
    int lvl, h, s, pos;
    levelOf(i, lvl, h, s, pos);
    int hh = h * h;
    const float* cp = (lvl == 0) ? c0 : (lvl == 1) ? c1 : (lvl == 2) ? c2
                      : (lvl == 3) ? c3 : c4;
    const float* base = cp + (size_t)b * NCLS * hh + pos;
    float4 best = make_float4(-1e30f, -1e30f, -1e30f, -1e30f);
    int bcx = 0, bcy = 0, bcz = 0, bcw = 0;
    #pragma unroll
    for (int c = 0; c < NCLS; ++c) {
        float4 v = *(const float4*)(base + (size_t)c * hh);
        float sx = sigmoidf(v.x), sy = sigmoidf(v.y);
        float sz = sigmoidf(v.z), sw = sigmoidf(v.w);
        if (sx > best.x) { best.x = sx; bcx = c; }
        if (sy > best.y) { best.y = sy; bcy = c; }
        if (sz > best.z) { best.z = sz; bcz = c; }
        if (sw > best.w) { best.w = sw; bcw = c; }
    }
    *(float4*)(scores + g) = best;
    *(uchar4*)(classes + g) = make_uchar4(
        (unsigned char)(bcx + 1), (unsigned char)(bcy + 1),
        (unsigned char)(bcz + 1), (unsigned char)(bcw + 1));
}

// ---- Kernel 2: fused hist + threshold + compact (one block per batch) -----------
// Two LDS sub-histograms (wave parity) halve hot-word atomic serialization.
__global__ __launch_bounds__(1024) void k_histTC(
    const float* __restrict__ scores,
    int* __restrict__ cnt, unsigned long long* __restrict__ cand)
{
    const int b   = blockIdx.x;
    const int tid = threadIdx.x;
    __shared__ unsigned int lhA[NBIN / 2];   // 64 KB packed u16
    __shared__ unsigned int lhB[NBIN / 2];   // 64 KB packed u16
    __shared__ unsigned int csum[1024];
    __shared__ int s_c, s_T, s_cnt;

    for (int i = tid; i < NBIN / 2; i += 1024) { lhA[i] = 0u; lhB[i] = 0u; }
    if (tid == 0) { s_c = 0; s_T = 0; s_cnt = 0; }
    __syncthreads();

    unsigned int* lh = (tid & 64) ? lhB : lhA;   // wave-parity split
    const float4* sv = (const float4*)(scores + (size_t)b * NANCH);
    for (int f4 = tid; f4 < NANCH / 4; f4 += 1024) {
        float4 v = sv[f4];
        unsigned int bin;
        bin = __float_as_uint(v.x) >> BSHIFT;
        atomicAdd(&lh[bin >> 1], 1u << ((bin & 1) << 4));
        bin = __float_as_uint(v.y) >> BSHIFT;
        atomicAdd(&lh[bin >> 1], 1u << ((bin & 1) << 4));
        bin = __float_as_uint(v.z) >> BSHIFT;
        atomicAdd(&lh[bin >> 1], 1u << ((bin & 1) << 4));
        bin = __float_as_uint(v.w) >> BSHIFT;
        atomicAdd(&lh[bin >> 1], 1u << ((bin & 1) << 4));
    }
    __syncthreads();

    // chunk sums: thread t owns bins [32t, 32t+32) = words [16t, 16t+16) of A+B
    unsigned int s = 0;
    #pragma unroll
    for (int k = 0; k < 16; ++k) {
        unsigned int wA = lhA[tid * 16 + k];
        unsigned int wB = lhB[tid * 16 + k];
        s += (wA & 0xFFFFu) + (wA >> 16) + (wB & 0xFFFFu) + (wB >> 16);
    }
    csum[tid] = s;
    __syncthreads();
    for (int d = 1; d < 1024; d <<= 1) {
        unsigned int add = (tid + d < 1024) ? csum[tid + d] : 0u;
        __syncthreads();
        csum[tid] += add;
        __syncthreads();
    }
    if (csum[tid] >= (unsigned)KTOP &&
        (tid == 1023 || csum[tid + 1] < (unsigned)KTOP))
        s_c = tid;
    __syncthreads();
    const int c = s_c;
    const unsigned int hi = (c < 1023) ? csum[c + 1] : 0u;

    if (tid < 64) {
        unsigned int bc = 0;
        if (tid < 32) {
            int bin = c * 32 + tid;
            int sh = (bin & 1) << 4;
            bc = ((lhA[bin >> 1] >> sh) & 0xFFFFu) + ((lhB[bin >> 1] >> sh) & 0xFFFFu);
        }
        unsigned int suf = bc;
        #pragma unroll
        for (int d = 1; d < 32; d <<= 1) {
            unsigned int o = __shfl_down(suf, d);
            if (tid + d < 32) suf += o;
        }
        unsigned int nxt = __shfl_down(suf, 1);
        if (tid < 32) {
            if (hi + suf >= (unsigned)KTOP &&
                (tid == 31 || hi + nxt < (unsigned)KTOP))
                s_T = c * 32 + tid;
        }
    }
    __syncthreads();
    const int T = s_T;

    // compact candidates to global cand (order irrelevant — rank-scatter later)
    for (int f4 = tid; f4 < NANCH / 4; f4 += 1024) {
        float4 v = sv[f4];
        unsigned int bits[4] = { __float_as_uint(v.x), __float_as_uint(v.y),
                                 __float_as_uint(v.z), __float_as_uint(v.w) };
        #pragma unroll
        for (int k = 0; k < 4; ++k) {
            if ((int)(bits[k] >> BSHIFT) >= T) {
                int p = atomicAdd(&s_cnt, 1);
                if (p < CAND) {
                    unsigned int idx = 4u * (unsigned int)f4 + (unsigned int)k;
                    cand[(size_t)b * CAND + p] =
                        ((unsigned long long)bits[k] << 32) |
                        (unsigned long long)(0xFFFFFFFFu - idx);
                }
            }
        }
    }
    __syncthreads();
    if (tid == 0) cnt[b * 16] = s_cnt;
}

// ---- Kernel 3: exact rank-scatter + lean decode (no LDS; uniform global reads) --
__global__ __launch_bounds__(256) void k_rankdec(
    const unsigned long long* __restrict__ cand, const int* __restrict__ cnt,
    const float* __restrict__ r0, const float* __restrict__ r1,
    const float* __restrict__ r2, const float* __restrict__ r3,
    const float* __restrict__ r4,
    const unsigned char* __restrict__ classes_all,
    float* __restrict__ tsc, int* __restrict__ tix,
    float* __restrict__ boxes, int* __restrict__ clstop)
{
    const int b  = blockIdx.y;
    const int ci = blockIdx.x * 256 + threadIdx.x;   // 0..2047
    int n = cnt[b * 16]; if (n > CAND) n = CAND;
    if (ci >= n) return;

    const unsigned long long* cb = cand + (size_t)b * CAND;
    const unsigned long long my = cb[ci];

    // rank = #{j: key_j > my}; j is wave-uniform -> scalar/K$-cached loads,
    // no dependency into the loads -> fully pipelined.
    int rank = 0;
    #pragma unroll 4
    for (int j = 0; j < n; ++j)
        rank += (cb[j] > my) ? 1 : 0;
    if (rank >= KTOP) return;

    const int g   = b * KTOP + rank;
    const int idx = (int)(0xFFFFFFFFu - (unsigned int)(my & 0xFFFFFFFFull));
    tsc[g] = __uint_as_float((unsigned int)(my >> 32));
    tix[g] = idx;
    clstop[g] = (int)classes_all[(size_t)b * NANCH + idx];

    int lvl, h, s, pos;
    levelOf(idx, lvl, h, s, pos);
    int y = pos / h, x = pos - y * h;
    int hh = h * h;
    const float* rp = (lvl == 0) ? r0 : (lvl == 1) ? r1 : (lvl == 2) ? r2
                      : (lvl == 3) ? r3 : r4;
    const float* rb = rp + (size_t)b * 5 * hh + pos;
    float fs = (float)s;
    float rr0 = rb[0] * fs;
    float rr1 = rb[(size_t)hh] * fs;
    float rr2 = rb[(size_t)2 * hh] * fs;
    float rr3 = rb[(size_t)3 * hh] * fs;
    float cx = (float)(x * s + (s >> 1));
    float cy = (float)(y * s + (s >> 1));
    float* op = boxes + (size_t)g * 5;
    op[0] = cx - rr0;
    op[1] = cy - rr1;
    op[2] = cx + rr2;
    op[3] = cy + rr3;
    // op[4] (theta) written by the theta role of k_masktheta
}

// ---- Kernel 4: FUSED mask + theta (independent: mask reads boxes[0..3],
// theta writes boxes[4]).  blockIdx.y < 16 -> mask slice; else theta slice. ------
__global__ __launch_bounds__(256) void k_masktheta(
    const float* __restrict__ boxes_in, unsigned long long* __restrict__ mask,
    const float* __restrict__ t0, const float* __restrict__ t1,
    const float* __restrict__ t2, const float* __restrict__ t3,
    const float* __restrict__ t4,
    const float* __restrict__ q0, const float* __restrict__ q1,
    const float* __restrict__ q2, const float* __restrict__ q3,
    const float* __restrict__ q4,
    const int* __restrict__ tix, float* __restrict__ boxes_theta)
{
    const int b = blockIdx.x;
    const int role = blockIdx.y;

    if (role < 16) {
        const int by = role;
        __shared__ float bx1[1024], by1[1024], bx2[1024], by2[1024], bar[1024];
        for (int r = threadIdx.x; r < 1024; r += 256) {
            float x1 = 0.f, y1 = 0.f, x2 = 0.f, y2 = 0.f;
            if (r < KTOP) {
                const float* p = boxes_in + ((size_t)(b * KTOP + r)) * 5;
                x1 = p[0]; y1 = p[1]; x2 = p[2]; y2 = p[3];
            }
            bx1[r] = x1; by1[r] = y1; bx2[r] = x2; by2[r] = y2;
            bar[r] = fmaxf(x2 - x1, 0.0f) * fmaxf(y2 - y1, 0.0f);
        }
        __syncthreads();

        const int l  = threadIdx.x & 63;
        const int wv = threadIdx.x >> 6;
        const int i  = (by << 6) + l;
        const float x1 = bx1[i], y1 = by1[i], x2 = bx2[i], y2 = by2[i], ai = bar[i];

        for (int w = by + wv; w < NWORDS; w += 4) {
            const int j0 = w << 6;
            unsigned long long m = 0ull;
            #pragma unroll 8
            for (int jj = 0; jj < 64; ++jj) {
                const int j = j0 + jj;
                float iw = fminf(x2, bx2[j]) - fmaxf(x1, bx1[j]);
                iw = fmaxf(iw, 0.0f);
                float ih = fminf(y2, by2[j]) - fmaxf(y1, by1[j]);
                ih = fmaxf(ih, 0.0f);
                float inter = iw * ih;
                float u = ai + bar[j] - inter;
                float iou = inter / fmaxf(u, 1e-8f);
                unsigned long long bit = (iou > 0.3f && j > i) ? 1ull : 0ull;
                m |= bit << jj;
            }
            mask[(((size_t)b * 1024 + i) << 4) + w] = m;
        }
    } else {
        int r = (role - 16) * 4 + (threadIdx.x >> 6);   // 0..999
        if (r >= KTOP) return;
        int lane = threadIdx.x & 63;
        int wid = b * KTOP + r;
        int idx = tix[wid];                              // wave-uniform

        int lvl, h, s, pos;
        levelOf(idx, lvl, h, s, pos);
        int hh = h * h;
        const float* tp = (lvl == 0) ? t0 : (lvl == 1) ? t1 : (lvl == 2) ? t2
                          : (lvl == 3) ? t3 : t4;
        const float* qp = (lvl == 0) ? q0 : (lvl == 1) ? q1 : (lvl == 2) ? q2
                          : (lvl == 3) ? q3 : q4;

        float v = -1e30f;
        if (lane < NTH)
            v = sigmoidf(tp[(size_t)b * NTH * hh + pos + (size_t)lane * hh]);
        float m = v;
        m = fmaxf(m, __shfl_xor(m, 1));
        m = fmaxf(m, __shfl_xor(m, 2));
        m = fmaxf(m, __shfl_xor(m, 4));
        m = fmaxf(m, __shfl_xor(m, 8));
        m = fmaxf(m, __shfl_xor(m, 16));
        m = fmaxf(m, __shfl_xor(m, 32));
        unsigned long long eq = __ballot(v == m);
        int bt = __builtin_ctzll(eq);                    // first-index tie-break
        float tr = qp[(size_t)b * hh + pos];
        if (lane == 0)
            boxes_theta[(size_t)wid * 5 + 4] = (float)(bt + 1) * 10.0f + tr;
    }
}

// ---- Kernel 5: greedy NMS — sparse exact chain, prefetched rows, one wave -------
#define LOADROW(R, W) do {                                                          \
    const ulonglong2* rp2 = (const ulonglong2*)(mask +                              \
        (((size_t)b * 1024 + ((W) << 6) + l) << 4));                                \
    _Pragma("unroll")                                                               \
    for (int p = 0; p < 8; ++p) {                                                   \
        ulonglong2 v = rp2[p]; R[2 * p] = v.x; R[2 * p + 1] = v.y;                  \
    }                                                                               \
} while (0)

#define PROC(W, R) do {                                                             \
    const unsigned long long rowword = R[W];                                        \
    unsigned long long zr = __ballot(rowword == 0ull);                              \
    unsigned long long remw = sremv[W];                                             \
    unsigned long long pend = vw[W] & ~remw;                                        \
    unsigned long long keptm = 0ull;                                                \
    while (pend) {                                                                  \
        unsigned long long nzp = pend & ~zr;                                        \
        if (!nzp) { keptm |= pend; break; }                                         \
        int jj = __builtin_ctzll(nzp);                                              \
        unsigned long long low = (1ull << jj); low = (low << 1) - 1ull;             \
        keptm |= pend & low;                                                        \
        remw |= shfl_u64(rowword, jj);                                              \
        pend &= ~low; pend &= ~remw;                                                \
    }                                                                               \
    if (l == 0) skeep[W] = keptm;                                                   \
    if ((keptm >> l) & 1ull) {                                                      \
        _Pragma("unroll")                                                           \
        for (int w2 = (W) + 1; w2 < NWORDS; ++w2)                                   \
            if (R[w2]) atomicOr64Shared(&sremv[w2], R[w2]);                         \
    }                                                                               \
} while (0)

__global__ __launch_bounds__(64) void k_nms(
    const unsigned long long* __restrict__ mask,   // [b][1024][16]
    const float* __restrict__ tsc, const int* __restrict__ clstop,
    const float* __restrict__ boxes, float* __restrict__ out)
{
    const int b = blockIdx.x;
    const int l = threadIdx.x;
    __shared__ unsigned long long sremv[NWORDS];
    __shared__ unsigned long long skeep[NWORDS];

    if (l < NWORDS) sremv[l] = 0ull;   // single wave: in-order LDS, no barrier

    unsigned long long vw[NWORDS];
    #pragma unroll
    for (int w = 0; w < NWORDS; ++w) {
        int i = (w << 6) + l;
        bool v = (i < KTOP) && (tsc[b * KTOP + i] >= 0.05f);
        vw[w] = __ballot(v);
    }

    unsigned long long rowA[NWORDS], rowB[NWORDS];
    LOADROW(rowA, 0);
    LOADROW(rowB, 1);   PROC(0, rowA);
    LOADROW(rowA, 2);   PROC(1, rowB);
    LOADROW(rowB, 3);   PROC(2, rowA);
    LOADROW(rowA, 4);   PROC(3, rowB);
    LOADROW(rowB, 5);   PROC(4, rowA);
    LOADROW(rowA, 6);   PROC(5, rowB);
    LOADROW(rowB, 7);   PROC(6, rowA);
    LOADROW(rowA, 8);   PROC(7, rowB);
    LOADROW(rowB, 9);   PROC(8, rowA);
    LOADROW(rowA, 10);  PROC(9, rowB);
    LOADROW(rowB, 11);  PROC(10, rowA);
    LOADROW(rowA, 12);  PROC(11, rowB);
    LOADROW(rowB, 13);  PROC(12, rowA);
    LOADROW(rowA, 14);  PROC(13, rowB);
    LOADROW(rowB, 15);  PROC(14, rowA);
    PROC(15, rowB);

    // fused masked output write
    #pragma unroll
    for (int w = 0; w < NWORDS; ++w) {
        int i = (w << 6) + l;
        if (i < KTOP) {
            int g = b * KTOP + i;
            float fk = (float)((skeep[w] >> l) & 1ull);
            out[g] = tsc[g] * fk;
            out[BATCH * KTOP + g] = (float)clstop[g] * fk;
            const float* bp = boxes + (size_t)g * 5;
            float* op = out + 2 * BATCH * KTOP + (size_t)g * 5;
            op[0] = bp[0] * fk;
            op[1] = bp[1] * fk;
            op[2] = bp[2] * fk;
            op[3] = bp[3] * fk;
            op[4] = bp[4] * fk;
        }
    }
}

extern "C" void kernel_launch(void* const* d_in, const int* in_sizes, int n_in,
                              void* d_out, int out_size, void* d_ws, size_t ws_size,
                              hipStream_t stream) {
    const float* c0 = (const float*)d_in[0];
    const float* c1 = (const float*)d_in[1];
    const float* c2 = (const float*)d_in[2];
    const float* c3 = (const float*)d_in[3];
    const float* c4 = (const float*)d_in[4];
    const float* r0 = (const float*)d_in[5];
    const float* r1 = (const float*)d_in[6];
    const float* r2 = (const float*)d_in[7];
    const float* r3 = (const float*)d_in[8];
    const float* r4 = (const float*)d_in[9];
    const float* t0 = (const float*)d_in[10];
    const float* t1 = (const float*)d_in[11];
    const float* t2 = (const float*)d_in[12];
    const float* t3 = (const float*)d_in[13];
    const float* t4 = (const float*)d_in[14];
    const float* q0 = (const float*)d_in[15];
    const float* q1 = (const float*)d_in[16];
    const float* q2 = (const float*)d_in[17];
    const float* q3 = (const float*)d_in[18];
    const float* q4 = (const float*)d_in[19];

    // Workspace layout, total 6,800,640 B. No aliasing, no zero pass at all:
    // hist lives in k_histTC's LDS; cnt written directly by k_histTC.
    char* ws = (char*)d_ws;
    float*              scores  = (float*)(ws + 0);               // 3,142,656
    unsigned char*      classes = (unsigned char*)(ws + 3142656); //   785,664
    int*                tcnt    = (int*)(ws + 3928320);           //     1,024
    unsigned long long* cand    = (unsigned long long*)(ws + 3929344); // 262,144
    float*              tsc     = (float*)(ws + 4191488);         //    64,000
    int*                tix     = (int*)(ws + 4255488);           //    64,000
    int*                clstop  = (int*)(ws + 4319488);           //    64,000
    float*              boxes   = (float*)(ws + 4383488);         //   320,000
    unsigned long long* mask    = (unsigned long long*)(ws + 4703488); // 2,097,152
    float*              out     = (float*)d_out;

    k_scores<<<(BATCH * NANCH / 4 + 255) / 256, 256, 0, stream>>>(
        c0, c1, c2, c3, c4, scores, classes);
    k_histTC<<<BATCH, 1024, 0, stream>>>(scores, tcnt, cand);
    k_rankdec<<<dim3(8, BATCH), 256, 0, stream>>>(
        cand, tcnt, r0, r1, r2, r3, r4, classes, tsc, tix, boxes, clstop);
    k_masktheta<<<dim3(BATCH, 16 + (KTOP + 3) / 4), 256, 0, stream>>>(
        boxes, mask, t0, t1, t2, t3, t4, q0, q1, q2, q3, q4, tix, boxes);
    k_nms<<<BATCH, 64, 0, stream>>>(mask, tsc, clstop, boxes, out);
}

// Round 18
// 111.141 us; speedup vs baseline: 1.1209x; 1.1209x over previous
//
#include <hip/hip_runtime.h>
#include <stdint.h>

#define NCLS   15
#define NTH    18
#define BATCH  16
#define NANCH  49104
#define KTOP   1000
#define NWORDS 16   // 16*64 = 1024 >= 1000
#define NBIN   32768
#define BSHIFT 15
#define CAND   2048

__device__ __forceinline__ float sigmoidf(float x) {
    return 1.0f / (1.0f + expf(-x));
}

__device__ __forceinline__ void levelOf(int i, int& lvl, int& h, int& s, int& pos) {
    if (i < 36864)      { lvl = 0; h = 192; s = 8;   pos = i; }
    else if (i < 46080) { lvl = 1; h = 96;  s = 16;  pos = i - 36864; }
    else if (i < 48384) { lvl = 2; h = 48;  s = 32;  pos = i - 46080; }
    else if (i < 48960) { lvl = 3; h = 24;  s = 64;  pos = i - 48384; }
    else                { lvl = 4; h = 12;  s = 128; pos = i - 48960; }
}

__device__ __forceinline__ unsigned long long shfl_u64(unsigned long long v, int src) {
    int lo = __shfl((int)(unsigned int)(v & 0xFFFFFFFFull), src);
    int hi = __shfl((int)(unsigned int)(v >> 32), src);
    return ((unsigned long long)(unsigned int)hi << 32) | (unsigned long long)(unsigned int)lo;
}

__device__ __forceinline__ void atomicOr64Shared(unsigned long long* p, unsigned long long v) {
    unsigned int* q = (unsigned int*)p;
    unsigned int lo = (unsigned int)v;
    unsigned int hi = (unsigned int)(v >> 32);
    if (lo) atomicOr(q, lo);
    if (hi) atomicOr(q + 1, hi);
}

// ---- Kernel 1: pure-stream scores + exact class argmax --------------------------
__global__ __launch_bounds__(256) void k_scores(
    const float* __restrict__ c0, const float* __restrict__ c1,
    const float* __restrict__ c2, const float* __restrict__ c3,
    const float* __restrict__ c4,
    float* __restrict__ scores, unsigned char* __restrict__ classes)
{
    int g4 = blockIdx.x * 256 + threadIdx.x;
    if (g4 >= BATCH * NANCH / 4) return;
    int g = g4 * 4;
    int b = g / NANCH;
    int i = g - b * NANCH;          // multiple of 4; level boundaries are too
    int lvl, h, s, pos;
    levelOf(i, lvl, h, s, pos);
    int hh = h * h;
    const float* cp = (lvl == 0) ? c0 : (lvl == 1) ? c1 : (lvl == 2) ? c2
                      : (lvl == 3) ? c3 : c4;
    const float* base = cp + (size_t)b * NCLS * hh + pos;
    float4 best = make_float4(-1e30f, -1e30f, -1e30f, -1e30f);
    int bcx = 0, bcy = 0, bcz = 0, bcw = 0;
    #pragma unroll
    for (int c = 0; c < NCLS; ++c) {
        float4 v = *(const float4*)(base + (size_t)c * hh);
        float sx = sigmoidf(v.x), sy = sigmoidf(v.y);
        float sz = sigmoidf(v.z), sw = sigmoidf(v.w);
        if (sx > best.x) { best.x = sx; bcx = c; }
        if (sy > best.y) { best.y = sy; bcy = c; }
        if (sz > best.z) { best.z = sz; bcz = c; }
        if (sw > best.w) { best.w = sw; bcw = c; }
    }
    *(float4*)(scores + g) = best;
    *(uchar4*)(classes + g) = make_uchar4(
        (unsigned char)(bcx + 1), (unsigned char)(bcy + 1),
        (unsigned char)(bcz + 1), (unsigned char)(bcw + 1));
}

// ---- Kernel 2: fused hist + threshold + compact (one block per batch) -----------
// Two LDS sub-histograms (wave parity) halve hot-word atomic serialization.
__global__ __launch_bounds__(1024) void k_histTC(
    const float* __restrict__ scores,
    int* __restrict__ cnt, unsigned long long* __restrict__ cand)
{
    const int b   = blockIdx.x;
    const int tid = threadIdx.x;
    __shared__ unsigned int lhA[NBIN / 2];   // 64 KB packed u16
    __shared__ unsigned int lhB[NBIN / 2];   // 64 KB packed u16
    __shared__ unsigned int csum[1024];
    __shared__ int s_c, s_T, s_cnt;

    for (int i = tid; i < NBIN / 2; i += 1024) { lhA[i] = 0u; lhB[i] = 0u; }
    if (tid == 0) { s_c = 0; s_T = 0; s_cnt = 0; }
    __syncthreads();

    unsigned int* lh = (tid & 64) ? lhB : lhA;   // wave-parity split
    const float4* sv = (const float4*)(scores + (size_t)b * NANCH);
    for (int f4 = tid; f4 < NANCH / 4; f4 += 1024) {
        float4 v = sv[f4];
        unsigned int bin;
        bin = __float_as_uint(v.x) >> BSHIFT;
        atomicAdd(&lh[bin >> 1], 1u << ((bin & 1) << 4));
        bin = __float_as_uint(v.y) >> BSHIFT;
        atomicAdd(&lh[bin >> 1], 1u << ((bin & 1) << 4));
        bin = __float_as_uint(v.z) >> BSHIFT;
        atomicAdd(&lh[bin >> 1], 1u << ((bin & 1) << 4));
        bin = __float_as_uint(v.w) >> BSHIFT;
        atomicAdd(&lh[bin >> 1], 1u << ((bin & 1) << 4));
    }
    __syncthreads();

    // chunk sums: thread t owns bins [32t, 32t+32) = words [16t, 16t+16) of A+B
    unsigned int s = 0;
    #pragma unroll
    for (int k = 0; k < 16; ++k) {
        unsigned int wA = lhA[tid * 16 + k];
        unsigned int wB = lhB[tid * 16 + k];
        s += (wA & 0xFFFFu) + (wA >> 16) + (wB & 0xFFFFu) + (wB >> 16);
    }
    csum[tid] = s;
    __syncthreads();
    for (int d = 1; d < 1024; d <<= 1) {
        unsigned int add = (tid + d < 1024) ? csum[tid + d] : 0u;
        __syncthreads();
        csum[tid] += add;
        __syncthreads();
    }
    if (csum[tid] >= (unsigned)KTOP &&
        (tid == 1023 || csum[tid + 1] < (unsigned)KTOP))
        s_c = tid;
    __syncthreads();
    const int c = s_c;
    const unsigned int hi = (c < 1023) ? csum[c + 1] : 0u;

    if (tid < 64) {
        unsigned int bc = 0;
        if (tid < 32) {
            int bin = c * 32 + tid;
            int sh = (bin & 1) << 4;
            bc = ((lhA[bin >> 1] >> sh) & 0xFFFFu) + ((lhB[bin >> 1] >> sh) & 0xFFFFu);
        }
        unsigned int suf = bc;
        #pragma unroll
        for (int d = 1; d < 32; d <<= 1) {
            unsigned int o = __shfl_down(suf, d);
            if (tid + d < 32) suf += o;
        }
        unsigned int nxt = __shfl_down(suf, 1);
        if (tid < 32) {
            if (hi + suf >= (unsigned)KTOP &&
                (tid == 31 || hi + nxt < (unsigned)KTOP))
                s_T = c * 32 + tid;
        }
    }
    __syncthreads();
    const int T = s_T;

    // compact candidates to global cand (order irrelevant — rank-scatter later)
    for (int f4 = tid; f4 < NANCH / 4; f4 += 1024) {
        float4 v = sv[f4];
        unsigned int bits[4] = { __float_as_uint(v.x), __float_as_uint(v.y),
                                 __float_as_uint(v.z), __float_as_uint(v.w) };
        #pragma unroll
        for (int k = 0; k < 4; ++k) {
            if ((int)(bits[k] >> BSHIFT) >= T) {
                int p = atomicAdd(&s_cnt, 1);
                if (p < CAND) {
                    unsigned int idx = 4u * (unsigned int)f4 + (unsigned int)k;
                    cand[(size_t)b * CAND + p] =
                        ((unsigned long long)bits[k] << 32) |
                        (unsigned long long)(0xFFFFFFFFu - idx);
                }
            }
        }
    }
    __syncthreads();
    if (tid == 0) cnt[b * 16] = s_cnt;
}

// ---- Kernel 3: exact rank-scatter + lean decode (LDS-staged broadcast loop) -----
__global__ __launch_bounds__(256) void k_rankdec(
    const unsigned long long* __restrict__ cand, const int* __restrict__ cnt,
    const float* __restrict__ r0, const float* __restrict__ r1,
    const float* __restrict__ r2, const float* __restrict__ r3,
    const float* __restrict__ r4,
    const unsigned char* __restrict__ classes_all,
    float* __restrict__ tsc, int* __restrict__ tix,
    float* __restrict__ boxes, int* __restrict__ clstop)
{
    const int b  = blockIdx.y;
    const int ci = blockIdx.x * 256 + threadIdx.x;   // 0..2047
    __shared__ unsigned long long keys[CAND];

    int n = cnt[b * 16]; if (n > CAND) n = CAND;
    for (int i = threadIdx.x; i < CAND; i += 256)
        keys[i] = (i < n) ? cand[(size_t)b * CAND + i] : 0ull;
    __syncthreads();

    const unsigned long long my = keys[ci];
    if (my == 0ull) return;                          // pad slot

    int rank = 0;
    #pragma unroll 8
    for (int j = 0; j < CAND; ++j)                   // wave-uniform j -> broadcast
        rank += (keys[j] > my) ? 1 : 0;
    if (rank >= KTOP) return;

    const int g   = b * KTOP + rank;
    const int idx = (int)(0xFFFFFFFFu - (unsigned int)(my & 0xFFFFFFFFull));
    tsc[g] = __uint_as_float((unsigned int)(my >> 32));
    tix[g] = idx;
    clstop[g] = (int)classes_all[(size_t)b * NANCH + idx];

    int lvl, h, s, pos;
    levelOf(idx, lvl, h, s, pos);
    int y = pos / h, x = pos - y * h;
    int hh = h * h;
    const float* rp = (lvl == 0) ? r0 : (lvl == 1) ? r1 : (lvl == 2) ? r2
                      : (lvl == 3) ? r3 : r4;
    const float* rb = rp + (size_t)b * 5 * hh + pos;
    float fs = (float)s;
    float rr0 = rb[0] * fs;
    float rr1 = rb[(size_t)hh] * fs;
    float rr2 = rb[(size_t)2 * hh] * fs;
    float rr3 = rb[(size_t)3 * hh] * fs;
    float cx = (float)(x * s + (s >> 1));
    float cy = (float)(y * s + (s >> 1));
    float* op = boxes + (size_t)g * 5;
    op[0] = cx - rr0;
    op[1] = cy - rr1;
    op[2] = cx + rr2;
    op[3] = cy + rr3;
    // op[4] (theta) written by the theta role of k_masktheta
}

// ---- Kernel 4: FUSED mask + theta (independent: mask reads boxes[0..3],
// theta writes boxes[4]).  blockIdx.y < 16 -> mask slice; else theta slice. ------
__global__ __launch_bounds__(256) void k_masktheta(
    const float* __restrict__ boxes_in, unsigned long long* __restrict__ mask,
    const float* __restrict__ t0, const float* __restrict__ t1,
    const float* __restrict__ t2, const float* __restrict__ t3,
    const float* __restrict__ t4,
    const float* __restrict__ q0, const float* __restrict__ q1,
    const float* __restrict__ q2, const float* __restrict__ q3,
    const float* __restrict__ q4,
    const int* __restrict__ tix, float* __restrict__ boxes_theta)
{
    const int b = blockIdx.x;
    const int role = blockIdx.y;

    if (role < 16) {
        const int by = role;
        __shared__ float bx1[1024], by1[1024], bx2[1024], by2[1024], bar[1024];
        for (int r = threadIdx.x; r < 1024; r += 256) {
            float x1 = 0.f, y1 = 0.f, x2 = 0.f, y2 = 0.f;
            if (r < KTOP) {
                const float* p = boxes_in + ((size_t)(b * KTOP + r)) * 5;
                x1 = p[0]; y1 = p[1]; x2 = p[2]; y2 = p[3];
            }
            bx1[r] = x1; by1[r] = y1; bx2[r] = x2; by2[r] = y2;
            bar[r] = fmaxf(x2 - x1, 0.0f) * fmaxf(y2 - y1, 0.0f);
        }
        __syncthreads();

        const int l  = threadIdx.x & 63;
        const int wv = threadIdx.x >> 6;
        const int i  = (by << 6) + l;
        const float x1 = bx1[i], y1 = by1[i], x2 = bx2[i], y2 = by2[i], ai = bar[i];

        for (int w = by + wv; w < NWORDS; w += 4) {
            const int j0 = w << 6;
            unsigned long long m = 0ull;
            #pragma unroll 8
            for (int jj = 0; jj < 64; ++jj) {
                const int j = j0 + jj;
                float iw = fminf(x2, bx2[j]) - fmaxf(x1, bx1[j]);
                iw = fmaxf(iw, 0.0f);
                float ih = fminf(y2, by2[j]) - fmaxf(y1, by1[j]);
                ih = fmaxf(ih, 0.0f);
                float inter = iw * ih;
                float u = ai + bar[j] - inter;
                float iou = inter / fmaxf(u, 1e-8f);
                unsigned long long bit = (iou > 0.3f && j > i) ? 1ull : 0ull;
                m |= bit << jj;
            }
            mask[(((size_t)b * 1024 + i) << 4) + w] = m;
        }
    } else {
        int r = (role - 16) * 4 + (threadIdx.x >> 6);   // 0..999
        if (r >= KTOP) return;
        int lane = threadIdx.x & 63;
        int wid = b * KTOP + r;
        int idx = tix[wid];                              // wave-uniform

        int lvl, h, s, pos;
        levelOf(idx, lvl, h, s, pos);
        int hh = h * h;
        const float* tp = (lvl == 0) ? t0 : (lvl == 1) ? t1 : (lvl == 2) ? t2
                          : (lvl == 3) ? t3 : t4;
        const float* qp = (lvl == 0) ? q0 : (lvl == 1) ? q1 : (lvl == 2) ? q2
                          : (lvl == 3) ? q3 : q4;

        float v = -1e30f;
        if (lane < NTH)
            v = sigmoidf(tp[(size_t)b * NTH * hh + pos + (size_t)lane * hh]);
        float m = v;
        m = fmaxf(m, __shfl_xor(m, 1));
        m = fmaxf(m, __shfl_xor(m, 2));
        m = fmaxf(m, __shfl_xor(m, 4));
        m = fmaxf(m, __shfl_xor(m, 8));
        m = fmaxf(m, __shfl_xor(m, 16));
        m = fmaxf(m, __shfl_xor(m, 32));
        unsigned long long eq = __ballot(v == m);
        int bt = __builtin_ctzll(eq);                    // first-index tie-break
        float tr = qp[(size_t)b * hh + pos];
        if (lane == 0)
            boxes_theta[(size_t)wid * 5 + 4] = (float)(bt + 1) * 10.0f + tr;
    }
}

// ---- Kernel 5: greedy NMS — sparse exact chain, prefetched rows, one wave -------
#define LOADROW(R, W) do {                                                          \
    const ulonglong2* rp2 = (const ulonglong2*)(mask +                              \
        (((size_t)b * 1024 + ((W) << 6) + l) << 4));                                \
    _Pragma("unroll")                                                               \
    for (int p = 0; p < 8; ++p) {                                                   \
        ulonglong2 v = rp2[p]; R[2 * p] = v.x; R[2 * p + 1] = v.y;                  \
    }                                                                               \
} while (0)

#define PROC(W, R) do {                                                             \
    const unsigned long long rowword = R[W];                                        \
    unsigned long long zr = __ballot(rowword == 0ull);                              \
    unsigned long long remw = sremv[W];                                             \
    unsigned long long pend = vw[W] & ~remw;                                        \
    unsigned long long keptm = 0ull;                                                \
    while (pend) {                                                                  \
        unsigned long long nzp = pend & ~zr;                                        \
        if (!nzp) { keptm |= pend; break; }                                         \
        int jj = __builtin_ctzll(nzp);                                              \
        unsigned long long low = (1ull << jj); low = (low << 1) - 1ull;             \
        keptm |= pend & low;                                                        \
        remw |= shfl_u64(rowword, jj);                                              \
        pend &= ~low; pend &= ~remw;                                                \
    }                                                                               \
    if (l == 0) skeep[W] = keptm;                                                   \
    if ((keptm >> l) & 1ull) {                                                      \
        _Pragma("unroll")                                                           \
        for (int w2 = (W) + 1; w2 < NWORDS; ++w2)                                   \
            if (R[w2]) atomicOr64Shared(&sremv[w2], R[w2]);                         \
    }                                                                               \
} while (0)

__global__ __launch_bounds__(64) void k_nms(
    const unsigned long long* __restrict__ mask,   // [b][1024][16]
    const float* __restrict__ tsc, const int* __restrict__ clstop,
    const float* __restrict__ boxes, float* __restrict__ out)
{
    const int b = blockIdx.x;
    const int l = threadIdx.x;
    __shared__ unsigned long long sremv[NWORDS];
    __shared__ unsigned long long skeep[NWORDS];

    if (l < NWORDS) sremv[l] = 0ull;   // single wave: in-order LDS, no barrier

    unsigned long long vw[NWORDS];
    #pragma unroll
    for (int w = 0; w < NWORDS; ++w) {
        int i = (w << 6) + l;
        bool v = (i < KTOP) && (tsc[b * KTOP + i] >= 0.05f);
        vw[w] = __ballot(v);
    }

    unsigned long long rowA[NWORDS], rowB[NWORDS];
    LOADROW(rowA, 0);
    LOADROW(rowB, 1);   PROC(0, rowA);
    LOADROW(rowA, 2);   PROC(1, rowB);
    LOADROW(rowB, 3);   PROC(2, rowA);
    LOADROW(rowA, 4);   PROC(3, rowB);
    LOADROW(rowB, 5);   PROC(4, rowA);
    LOADROW(rowA, 6);   PROC(5, rowB);
    LOADROW(rowB, 7);   PROC(6, rowA);
    LOADROW(rowA, 8);   PROC(7, rowB);
    LOADROW(rowB, 9);   PROC(8, rowA);
    LOADROW(rowA, 10);  PROC(9, rowB);
    LOADROW(rowB, 11);  PROC(10, rowA);
    LOADROW(rowA, 12);  PROC(11, rowB);
    LOADROW(rowB, 13);  PROC(12, rowA);
    LOADROW(rowA, 14);  PROC(13, rowB);
    LOADROW(rowB, 15);  PROC(14, rowA);
    PROC(15, rowB);

    // fused masked output write
    #pragma unroll
    for (int w = 0; w < NWORDS; ++w) {
        int i = (w << 6) + l;
        if (i < KTOP) {
            int g = b * KTOP + i;
            float fk = (float)((skeep[w] >> l) & 1ull);
            out[g] = tsc[g] * fk;
            out[BATCH * KTOP + g] = (float)clstop[g] * fk;
            const float* bp = boxes + (size_t)g * 5;
            float* op = out + 2 * BATCH * KTOP + (size_t)g * 5;
            op[0] = bp[0] * fk;
            op[1] = bp[1] * fk;
            op[2] = bp[2] * fk;
            op[3] = bp[3] * fk;
            op[4] = bp[4] * fk;
        }
    }
}

extern "C" void kernel_launch(void* const* d_in, const int* in_sizes, int n_in,
                              void* d_out, int out_size, void* d_ws, size_t ws_size,
                              hipStream_t stream) {
    const float* c0 = (const float*)d_in[0];
    const float* c1 = (const float*)d_in[1];
    const float* c2 = (const float*)d_in[2];
    const float* c3 = (const float*)d_in[3];
    const float* c4 = (const float*)d_in[4];
    const float* r0 = (const float*)d_in[5];
    const float* r1 = (const float*)d_in[6];
    const float* r2 = (const float*)d_in[7];
    const float* r3 = (const float*)d_in[8];
    const float* r4 = (const float*)d_in[9];
    const float* t0 = (const float*)d_in[10];
    const float* t1 = (const float*)d_in[11];
    const float* t2 = (const float*)d_in[12];
    const float* t3 = (const float*)d_in[13];
    const float* t4 = (const float*)d_in[14];
    const float* q0 = (const float*)d_in[15];
    const float* q1 = (const float*)d_in[16];
    const float* q2 = (const float*)d_in[17];
    const float* q3 = (const float*)d_in[18];
    const float* q4 = (const float*)d_in[19];

    // Workspace layout, total 6,800,640 B. No aliasing, no zero pass at all:
    // hist lives in k_histTC's LDS; cnt written directly by k_histTC.
    char* ws = (char*)d_ws;
    float*              scores  = (float*)(ws + 0);               // 3,142,656
    unsigned char*      classes = (unsigned char*)(ws + 3142656); //   785,664
    int*                tcnt    = (int*)(ws + 3928320);           //     1,024
    unsigned long long* cand    = (unsigned long long*)(ws + 3929344); // 262,144
    float*              tsc     = (float*)(ws + 4191488);         //    64,000
    int*                tix     = (int*)(ws + 4255488);           //    64,000
    int*                clstop  = (int*)(ws + 4319488);           //    64,000
    float*              boxes   = (float*)(ws + 4383488);         //   320,000
    unsigned long long* mask    = (unsigned long long*)(ws + 4703488); // 2,097,152
    float*              out     = (float*)d_out;

    k_scores<<<(BATCH * NANCH / 4 + 255) / 256, 256, 0, stream>>>(
        c0, c1, c2, c3, c4, scores, classes);
    k_histTC<<<BATCH, 1024, 0, stream>>>(scores, tcnt, cand);
    k_rankdec<<<dim3(8, BATCH), 256, 0, stream>>>(
        cand, tcnt, r0, r1, r2, r3, r4, classes, tsc, tix, boxes, clstop);
    k_masktheta<<<dim3(BATCH, 16 + (KTOP + 3) / 4), 256, 0, stream>>>(
        boxes, mask, t0, t1, t2, t3, t4, q0, q1, q2, q3, q4, tix, boxes);
    k_nms<<<BATCH, 64, 0, stream>>>(mask, tsc, clstop, boxes, out);
}

// Round 19
// 105.583 us; speedup vs baseline: 1.1799x; 1.0526x over previous
//
#include <hip/hip_runtime.h>
#include <stdint.h>

#define NCLS   15
#define NTH    18
#define BATCH  16
#define NANCH  49104
#define KTOP   1000
#define NWORDS 16   // 16*64 = 1024 >= 1000
#define NBIN   32768
#define BSHIFT 15
#define CAND   2048

__device__ __forceinline__ float sigmoidf(float x) {
    return 1.0f / (1.0f + expf(-x));
}

__device__ __forceinline__ void levelOf(int i, int& lvl, int& h, int& s, int& pos) {
    if (i < 36864)      { lvl = 0; h = 192; s = 8;   pos = i; }
    else if (i < 46080) { lvl = 1; h = 96;  s = 16;  pos = i - 36864; }
    else if (i < 48384) { lvl = 2; h = 48;  s = 32;  pos = i - 46080; }
    else if (i < 48960) { lvl = 3; h = 24;  s = 64;  pos = i - 48384; }
    else                { lvl = 4; h = 12;  s = 128; pos = i - 48960; }
}

__device__ __forceinline__ unsigned long long shfl_u64(unsigned long long v, int src) {
    int lo = __shfl((int)(unsigned int)(v & 0xFFFFFFFFull), src);
    int hi = __shfl((int)(unsigned int)(v >> 32), src);
    return ((unsigned long long)(unsigned int)hi << 32) | (unsigned long long)(unsigned int)lo;
}

__device__ __forceinline__ void atomicOr64Shared(unsigned long long* p, unsigned long long v) {
    unsigned int* q = (unsigned int*)p;
    unsigned int lo = (unsigned int)v;
    unsigned int hi = (unsigned int)(v >> 32);
    if (lo) atomicOr(q, lo);
    if (hi) atomicOr(q + 1, hi);
}

// ---- Kernel 1: pure-stream scores + exact class argmax --------------------------
__global__ __launch_bounds__(256) void k_scores(
    const float* __restrict__ c0, const float* __restrict__ c1,
    const float* __restrict__ c2, const float* __restrict__ c3,
    const float* __restrict__ c4,
    float* __restrict__ scores, unsigned char* __restrict__ classes)
{
    int g4 = blockIdx.x * 256 + threadIdx.x;
    if (g4 >= BATCH * NANCH / 4) return;
    int g = g4 * 4;
    int b = g / NANCH;
    int i = g - b * NANCH;          // multiple of 4; level boundaries are too
    int lvl, h, s, pos;
    levelOf(i, lvl, h, s, pos);
    int hh = h * h;
    const float* cp = (lvl == 0) ? c0 : (lvl == 1) ? c1 : (lvl == 2) ? c2
                      : (lvl == 3) ? c3 : c4;
    const float* base = cp + (size_t)b * NCLS * hh + pos;
    float4 best = make_float4(-1e30f, -1e30f, -1e30f, -1e30f);
    int bcx = 0, bcy = 0, bcz = 0, bcw = 0;
    #pragma unroll
    for (int c = 0; c < NCLS; ++c) {
        float4 v = *(const float4*)(base + (size_t)c * hh);
        float sx = sigmoidf(v.x), sy = sigmoidf(v.y);
        float sz = sigmoidf(v.z), sw = sigmoidf(v.w);
        if (sx > best.x) { best.x = sx; bcx = c; }
        if (sy > best.y) { best.y = sy; bcy = c; }
        if (sz > best.z) { best.z = sz; bcz = c; }
        if (sw > best.w) { best.w = sw; bcw = c; }
    }
    *(float4*)(scores + g) = best;
    *(uchar4*)(classes + g) = make_uchar4(
        (unsigned char)(bcx + 1), (unsigned char)(bcy + 1),
        (unsigned char)(bcz + 1), (unsigned char)(bcw + 1));
}

// ---- Kernel 2: per-batch histogram + threshold (hierarchical wave scan) ---------
__global__ __launch_bounds__(1024) void k_histT(
    const float* __restrict__ scores, int* __restrict__ tbin, int* __restrict__ tcnt)
{
    const int b   = blockIdx.x;
    const int tid = threadIdx.x;
    __shared__ unsigned int lhA[NBIN / 2];   // 64 KB packed u16
    __shared__ unsigned int lhB[NBIN / 2];   // 64 KB packed u16
    __shared__ unsigned int ssuf[1024];
    __shared__ unsigned int wtot[16], winc[16];
    __shared__ int s_c, s_T;

    for (int i = tid; i < NBIN / 2; i += 1024) { lhA[i] = 0u; lhB[i] = 0u; }
    if (tid == 0) { s_c = 0; s_T = 0; tcnt[b * 16] = 0; }
    __syncthreads();

    unsigned int* lh = (tid & 64) ? lhB : lhA;   // wave-parity split
    const float4* sv = (const float4*)(scores + (size_t)b * NANCH);
    for (int f4 = tid; f4 < NANCH / 4; f4 += 1024) {
        float4 v = sv[f4];
        unsigned int bin;
        bin = __float_as_uint(v.x) >> BSHIFT;
        atomicAdd(&lh[bin >> 1], 1u << ((bin & 1) << 4));
        bin = __float_as_uint(v.y) >> BSHIFT;
        atomicAdd(&lh[bin >> 1], 1u << ((bin & 1) << 4));
        bin = __float_as_uint(v.z) >> BSHIFT;
        atomicAdd(&lh[bin >> 1], 1u << ((bin & 1) << 4));
        bin = __float_as_uint(v.w) >> BSHIFT;
        atomicAdd(&lh[bin >> 1], 1u << ((bin & 1) << 4));
    }
    __syncthreads();

    // chunk sum: thread owns bins [32t, 32t+32) = words [16t,16t+16) of A+B
    unsigned int s = 0;
    #pragma unroll
    for (int k = 0; k < 16; ++k) {
        unsigned int wA = lhA[tid * 16 + k];
        unsigned int wB = lhB[tid * 16 + k];
        s += (wA & 0xFFFFu) + (wA >> 16) + (wB & 0xFFFFu) + (wB >> 16);
    }

    // hierarchical suffix scan: per-wave shfl scan + 16 wave-totals
    const int lane = tid & 63, wv = tid >> 6;
    unsigned int suf = s;
    #pragma unroll
    for (int d = 1; d < 64; d <<= 1) {
        unsigned int o = __shfl_down(suf, d);
        if (lane + d < 64) suf += o;
    }
    if (lane == 0) wtot[wv] = suf;
    __syncthreads();
    if (tid < 16) {
        unsigned int sw = wtot[tid];
        #pragma unroll
        for (int d = 1; d < 16; d <<= 1) {
            unsigned int o = __shfl_down(sw, d);
            if (tid + d < 16) sw += o;
        }
        winc[tid] = sw;                      // inclusive wave-suffix
    }
    __syncthreads();
    unsigned int myssuf = suf + ((wv < 15) ? winc[wv + 1] : 0u);
    ssuf[tid] = myssuf;
    __syncthreads();
    if (myssuf >= (unsigned)KTOP &&
        (tid == 1023 || ssuf[tid + 1] < (unsigned)KTOP))
        s_c = tid;
    __syncthreads();
    const int c = s_c;
    const unsigned int hi = (c < 1023) ? ssuf[c + 1] : 0u;

    // fine scan within chunk c (32 bins, one wave)
    if (tid < 64) {
        unsigned int bc = 0;
        if (tid < 32) {
            int bin = c * 32 + tid;
            int sh = (bin & 1) << 4;
            bc = ((lhA[bin >> 1] >> sh) & 0xFFFFu) + ((lhB[bin >> 1] >> sh) & 0xFFFFu);
        }
        unsigned int sf = bc;
        #pragma unroll
        for (int d = 1; d < 32; d <<= 1) {
            unsigned int o = __shfl_down(sf, d);
            if (tid + d < 32) sf += o;
        }
        unsigned int nxt = __shfl_down(sf, 1);
        if (tid < 32) {
            if (hi + sf >= (unsigned)KTOP &&
                (tid == 31 || hi + nxt < (unsigned)KTOP))
                s_T = c * 32 + tid;
        }
    }
    __syncthreads();
    if (tid == 0) tbin[b] = s_T;
}

// ---- Kernel 3: compact candidates — block-aggregated, padded counters -----------
__global__ __launch_bounds__(256) void k_compact(
    const float* __restrict__ scores, const int* __restrict__ tbin,
    int* __restrict__ cnt, unsigned long long* __restrict__ cand)
{
    const int b = blockIdx.y;
    const int t4 = blockIdx.x * 256 + threadIdx.x;   // float4 index within batch
    __shared__ int lcnt;
    __shared__ int lbase;
    if (threadIdx.x == 0) lcnt = 0;
    __syncthreads();

    const int T = tbin[b];
    const bool in = (t4 < NANCH / 4);
    float4 v = make_float4(0.f, 0.f, 0.f, 0.f);
    if (in) v = *(const float4*)(scores + (size_t)b * NANCH + 4 * (size_t)t4);
    unsigned int bits[4] = { __float_as_uint(v.x), __float_as_uint(v.y),
                             __float_as_uint(v.z), __float_as_uint(v.w) };
    int rank[4];
    #pragma unroll
    for (int k = 0; k < 4; ++k) {
        bool pass = in && ((int)(bits[k] >> BSHIFT) >= T);
        rank[k] = pass ? atomicAdd(&lcnt, 1) : -1;
    }
    __syncthreads();
    if (threadIdx.x == 0) lbase = atomicAdd(&cnt[b * 16], lcnt);
    __syncthreads();
    const int base = lbase;
    #pragma unroll
    for (int k = 0; k < 4; ++k) {
        if (rank[k] >= 0) {
            int p = base + rank[k];
            if (p < CAND) {
                unsigned int idx = 4u * (unsigned int)t4 + (unsigned int)k;
                cand[(size_t)b * CAND + p] =
                    ((unsigned long long)bits[k] << 32) |
                    (unsigned long long)(0xFFFFFFFFu - idx);
            }
        }
    }
}

// ---- Kernel 4: exact rank-scatter + lean decode (LDS-staged broadcast loop) -----
__global__ __launch_bounds__(256) void k_rankdec(
    const unsigned long long* __restrict__ cand, const int* __restrict__ cnt,
    const float* __restrict__ r0, const float* __restrict__ r1,
    const float* __restrict__ r2, const float* __restrict__ r3,
    const float* __restrict__ r4,
    const unsigned char* __restrict__ classes_all,
    float* __restrict__ tsc, int* __restrict__ tix,
    float* __restrict__ boxes, int* __restrict__ clstop)
{
    const int b  = blockIdx.y;
    const int ci = blockIdx.x * 256 + threadIdx.x;   // 0..2047
    __shared__ unsigned long long keys[CAND];

    int n = cnt[b * 16]; if (n > CAND) n = CAND;
    for (int i = threadIdx.x; i < CAND; i += 256)
        keys[i] = (i < n) ? cand[(size_t)b * CAND + i] : 0ull;
    __syncthreads();

    const unsigned long long my = keys[ci];
    if (my == 0ull) return;                          // pad slot

    int rank = 0;
    #pragma unroll 8
    for (int j = 0; j < CAND; ++j)                   // wave-uniform j -> broadcast
        rank += (keys[j] > my) ? 1 : 0;
    if (rank >= KTOP) return;

    const int g   = b * KTOP + rank;
    const int idx = (int)(0xFFFFFFFFu - (unsigned int)(my & 0xFFFFFFFFull));
    tsc[g] = __uint_as_float((unsigned int)(my >> 32));
    tix[g] = idx;
    clstop[g] = (int)classes_all[(size_t)b * NANCH + idx];

    int lvl, h, s, pos;
    levelOf(idx, lvl, h, s, pos);
    int y = pos / h, x = pos - y * h;
    int hh = h * h;
    const float* rp = (lvl == 0) ? r0 : (lvl == 1) ? r1 : (lvl == 2) ? r2
                      : (lvl == 3) ? r3 : r4;
    const float* rb = rp + (size_t)b * 5 * hh + pos;
    float fs = (float)s;
    float rr0 = rb[0] * fs;
    float rr1 = rb[(size_t)hh] * fs;
    float rr2 = rb[(size_t)2 * hh] * fs;
    float rr3 = rb[(size_t)3 * hh] * fs;
    float cx = (float)(x * s + (s >> 1));
    float cy = (float)(y * s + (s >> 1));
    float* op = boxes + (size_t)g * 5;
    op[0] = cx - rr0;
    op[1] = cy - rr1;
    op[2] = cx + rr2;
    op[3] = cy + rr3;
    // op[4] (theta) written by the theta role of k_masktheta
}

// ---- Kernel 5: FUSED mask + theta (independent: mask reads boxes[0..3],
// theta writes boxes[4]).  blockIdx.y < 16 -> mask slice; else theta slice. ------
__global__ __launch_bounds__(256) void k_masktheta(
    const float* __restrict__ boxes_in, unsigned long long* __restrict__ mask,
    const float* __restrict__ t0, const float* __restrict__ t1,
    const float* __restrict__ t2, const float* __restrict__ t3,
    const float* __restrict__ t4,
    const float* __restrict__ q0, const float* __restrict__ q1,
    const float* __restrict__ q2, const float* __restrict__ q3,
    const float* __restrict__ q4,
    const int* __restrict__ tix, float* __restrict__ boxes_theta)
{
    const int b = blockIdx.x;
    const int role = blockIdx.y;

    if (role < 16) {
        const int by = role;
        __shared__ float bx1[1024], by1[1024], bx2[1024], by2[1024], bar[1024];
        for (int r = threadIdx.x; r < 1024; r += 256) {
            float x1 = 0.f, y1 = 0.f, x2 = 0.f, y2 = 0.f;
            if (r < KTOP) {
                const float* p = boxes_in + ((size_t)(b * KTOP + r)) * 5;
                x1 = p[0]; y1 = p[1]; x2 = p[2]; y2 = p[3];
            }
            bx1[r] = x1; by1[r] = y1; bx2[r] = x2; by2[r] = y2;
            bar[r] = fmaxf(x2 - x1, 0.0f) * fmaxf(y2 - y1, 0.0f);
        }
        __syncthreads();

        const int l  = threadIdx.x & 63;
        const int wv = threadIdx.x >> 6;
        const int i  = (by << 6) + l;
        const float x1 = bx1[i], y1 = by1[i], x2 = bx2[i], y2 = by2[i], ai = bar[i];

        for (int w = by + wv; w < NWORDS; w += 4) {
            const int j0 = w << 6;
            unsigned long long m = 0ull;
            #pragma unroll 8
            for (int jj = 0; jj < 64; ++jj) {
                const int j = j0 + jj;
                float iw = fminf(x2, bx2[j]) - fmaxf(x1, bx1[j]);
                iw = fmaxf(iw, 0.0f);
                float ih = fminf(y2, by2[j]) - fmaxf(y1, by1[j]);
                ih = fmaxf(ih, 0.0f);
                float inter = iw * ih;
                float u = ai + bar[j] - inter;
                float iou = inter / fmaxf(u, 1e-8f);
                unsigned long long bit = (iou > 0.3f && j > i) ? 1ull : 0ull;
                m |= bit << jj;
            }
            mask[(((size_t)b * 1024 + i) << 4) + w] = m;
        }
    } else {
        int r = (role - 16) * 4 + (threadIdx.x >> 6);   // 0..999
        if (r >= KTOP) return;
        int lane = threadIdx.x & 63;
        int wid = b * KTOP + r;
        int idx = tix[wid];                              // wave-uniform

        int lvl, h, s, pos;
        levelOf(idx, lvl, h, s, pos);
        int hh = h * h;
        const float* tp = (lvl == 0) ? t0 : (lvl == 1) ? t1 : (lvl == 2) ? t2
                          : (lvl == 3) ? t3 : t4;
        const float* qp = (lvl == 0) ? q0 : (lvl == 1) ? q1 : (lvl == 2) ? q2
                          : (lvl == 3) ? q3 : q4;

        float v = -1e30f;
        if (lane < NTH)
            v = sigmoidf(tp[(size_t)b * NTH * hh + pos + (size_t)lane * hh]);
        float m = v;
        m = fmaxf(m, __shfl_xor(m, 1));
        m = fmaxf(m, __shfl_xor(m, 2));
        m = fmaxf(m, __shfl_xor(m, 4));
        m = fmaxf(m, __shfl_xor(m, 8));
        m = fmaxf(m, __shfl_xor(m, 16));
        m = fmaxf(m, __shfl_xor(m, 32));
        unsigned long long eq = __ballot(v == m);
        int bt = __builtin_ctzll(eq);                    // first-index tie-break
        float tr = qp[(size_t)b * hh + pos];
        if (lane == 0)
            boxes_theta[(size_t)wid * 5 + 4] = (float)(bt + 1) * 10.0f + tr;
    }
}

// ---- Kernel 6: greedy NMS — sparse exact chain, prefetched rows, one wave -------
#define LOADROW(R, W) do {                                                          \
    const ulonglong2* rp2 = (const ulonglong2*)(mask +                              \
        (((size_t)b * 1024 + ((W) << 6) + l) << 4));                                \
    _Pragma("unroll")                                                               \
    for (int p = 0; p < 8; ++p) {                                                   \
        ulonglong2 v = rp2[p]; R[2 * p] = v.x; R[2 * p + 1] = v.y;                  \
    }                                                                               \
} while (0)

#define PROC(W, R) do {                                                             \
    const unsigned long long rowword = R[W];                                        \
    unsigned long long zr = __ballot(rowword == 0ull);                              \
    unsigned long long remw = sremv[W];                                             \
    unsigned long long pend = vw[W] & ~remw;                                        \
    unsigned long long keptm = 0ull;                                                \
    while (pend) {                                                                  \
        unsigned long long nzp = pend & ~zr;                                        \
        if (!nzp) { keptm |= pend; break; }                                         \
        int jj = __builtin_ctzll(nzp);                                              \
        unsigned long long low = (1ull << jj); low = (low << 1) - 1ull;             \
        keptm |= pend & low;                                                        \
        remw |= shfl_u64(rowword, jj);                                              \
        pend &= ~low; pend &= ~remw;                                                \
    }                                                                               \
    if (l == 0) skeep[W] = keptm;                                                   \
    if ((keptm >> l) & 1ull) {                                                      \
        _Pragma("unroll")                                                           \
        for (int w2 = (W) + 1; w2 < NWORDS; ++w2)                                   \
            if (R[w2]) atomicOr64Shared(&sremv[w2], R[w2]);                         \
    }                                                                               \
} while (0)

__global__ __launch_bounds__(64) void k_nms(
    const unsigned long long* __restrict__ mask,   // [b][1024][16]
    const float* __restrict__ tsc, const int* __restrict__ clstop,
    const float* __restrict__ boxes, float* __restrict__ out)
{
    const int b = blockIdx.x;
    const int l = threadIdx.x;
    __shared__ unsigned long long sremv[NWORDS];
    __shared__ unsigned long long skeep[NWORDS];

    if (l < NWORDS) sremv[l] = 0ull;   // single wave: in-order LDS, no barrier

    unsigned long long vw[NWORDS];
    #pragma unroll
    for (int w = 0; w < NWORDS; ++w) {
        int i = (w << 6) + l;
        bool v = (i < KTOP) && (tsc[b * KTOP + i] >= 0.05f);
        vw[w] = __ballot(v);
    }

    unsigned long long rowA[NWORDS], rowB[NWORDS];
    LOADROW(rowA, 0);
    LOADROW(rowB, 1);   PROC(0, rowA);
    LOADROW(rowA, 2);   PROC(1, rowB);
    LOADROW(rowB, 3);   PROC(2, rowA);
    LOADROW(rowA, 4);   PROC(3, rowB);
    LOADROW(rowB, 5);   PROC(4, rowA);
    LOADROW(rowA, 6);   PROC(5, rowB);
    LOADROW(rowB, 7);   PROC(6, rowA);
    LOADROW(rowA, 8);   PROC(7, rowB);
    LOADROW(rowB, 9);   PROC(8, rowA);
    LOADROW(rowA, 10);  PROC(9, rowB);
    LOADROW(rowB, 11);  PROC(10, rowA);
    LOADROW(rowA, 12);  PROC(11, rowB);
    LOADROW(rowB, 13);  PROC(12, rowA);
    LOADROW(rowA, 14);  PROC(13, rowB);
    LOADROW(rowB, 15);  PROC(14, rowA);
    PROC(15, rowB);

    // fused masked output write
    #pragma unroll
    for (int w = 0; w < NWORDS; ++w) {
        int i = (w << 6) + l;
        if (i < KTOP) {
            int g = b * KTOP + i;
            float fk = (float)((skeep[w] >> l) & 1ull);
            out[g] = tsc[g] * fk;
            out[BATCH * KTOP + g] = (float)clstop[g] * fk;
            const float* bp = boxes + (size_t)g * 5;
            float* op = out + 2 * BATCH * KTOP + (size_t)g * 5;
            op[0] = bp[0] * fk;
            op[1] = bp[1] * fk;
            op[2] = bp[2] * fk;
            op[3] = bp[3] * fk;
            op[4] = bp[4] * fk;
        }
    }
}

extern "C" void kernel_launch(void* const* d_in, const int* in_sizes, int n_in,
                              void* d_out, int out_size, void* d_ws, size_t ws_size,
                              hipStream_t stream) {
    const float* c0 = (const float*)d_in[0];
    const float* c1 = (const float*)d_in[1];
    const float* c2 = (const float*)d_in[2];
    const float* c3 = (const float*)d_in[3];
    const float* c4 = (const float*)d_in[4];
    const float* r0 = (const float*)d_in[5];
    const float* r1 = (const float*)d_in[6];
    const float* r2 = (const float*)d_in[7];
    const float* r3 = (const float*)d_in[8];
    const float* r4 = (const float*)d_in[9];
    const float* t0 = (const float*)d_in[10];
    const float* t1 = (const float*)d_in[11];
    const float* t2 = (const float*)d_in[12];
    const float* t3 = (const float*)d_in[13];
    const float* t4 = (const float*)d_in[14];
    const float* q0 = (const float*)d_in[15];
    const float* q1 = (const float*)d_in[16];
    const float* q2 = (const float*)d_in[17];
    const float* q3 = (const float*)d_in[18];
    const float* q4 = (const float*)d_in[19];

    // Workspace layout, total 6,800,704 B. No aliasing, no zero pass:
    // hist lives in k_histT's LDS; tcnt zeroed by k_histT before k_compact.
    char* ws = (char*)d_ws;
    float*              scores  = (float*)(ws + 0);               // 3,142,656
    unsigned char*      classes = (unsigned char*)(ws + 3142656); //   785,664
    int*                tcnt    = (int*)(ws + 3928320);           //     1,024
    int*                tbin    = (int*)(ws + 3929344);           //        64
    unsigned long long* cand    = (unsigned long long*)(ws + 3929408); // 262,144
    float*              tsc     = (float*)(ws + 4191552);         //    64,000
    int*                tix     = (int*)(ws + 4255552);           //    64,000
    int*                clstop  = (int*)(ws + 4319552);           //    64,000
    float*              boxes   = (float*)(ws + 4383552);         //   320,000
    unsigned long long* mask    = (unsigned long long*)(ws + 4703552); // 2,097,152
    float*              out     = (float*)d_out;

    k_scores<<<(BATCH * NANCH / 4 + 255) / 256, 256, 0, stream>>>(
        c0, c1, c2, c3, c4, scores, classes);
    k_histT<<<BATCH, 1024, 0, stream>>>(scores, tbin, tcnt);
    k_compact<<<dim3(48, BATCH), 256, 0, stream>>>(scores, tbin, tcnt, cand);
    k_rankdec<<<dim3(8, BATCH), 256, 0, stream>>>(
        cand, tcnt, r0, r1, r2, r3, r4, classes, tsc, tix, boxes, clstop);
    k_masktheta<<<dim3(BATCH, 16 + (KTOP + 3) / 4), 256, 0, stream>>>(
        boxes, mask, t0, t1, t2, t3, t4, q0, q1, q2, q3, q4, tix, boxes);
    k_nms<<<BATCH, 64, 0, stream>>>(mask, tsc, clstop, boxes, out);
}

// Round 20
// 102.858 us; speedup vs baseline: 1.2111x; 1.0265x over previous
//
#include <hip/hip_runtime.h>
#include <stdint.h>

#define NCLS   15
#define NTH    18
#define BATCH  16
#define NANCH  49104
#define KTOP   1000
#define NWORDS 16   // 16*64 = 1024 >= 1000
#define NBIN   32768
#define BSHIFT 15
#define CAND   2048

__device__ __forceinline__ float sigmoidf(float x) {
    return 1.0f / (1.0f + expf(-x));
}

__device__ __forceinline__ void levelOf(int i, int& lvl, int& h, int& s, int& pos) {
    if (i < 36864)      { lvl = 0; h = 192; s = 8;   pos = i; }
    else if (i < 46080) { lvl = 1; h = 96;  s = 16;  pos = i - 36864; }
    else if (i < 48384) { lvl = 2; h = 48;  s = 32;  pos = i - 46080; }
    else if (i < 48960) { lvl = 3; h = 24;  s = 64;  pos = i - 48384; }
    else                { lvl = 4; h = 12;  s = 128; pos = i - 48960; }
}

__device__ __forceinline__ unsigned long long shfl_u64(unsigned long long v, int src) {
    int lo = __shfl((int)(unsigned int)(v & 0xFFFFFFFFull), src);
    int hi = __shfl((int)(unsigned int)(v >> 32), src);
    return ((unsigned long long)(unsigned int)hi << 32) | (unsigned long long)(unsigned int)lo;
}

__device__ __forceinline__ void atomicOr64Shared(unsigned long long* p, unsigned long long v) {
    unsigned int* q = (unsigned int*)p;
    unsigned int lo = (unsigned int)v;
    unsigned int hi = (unsigned int)(v >> 32);
    if (lo) atomicOr(q, lo);
    if (hi) atomicOr(q + 1, hi);
}

// ---- Kernel 1: pure-stream scores + exact class argmax --------------------------
__global__ __launch_bounds__(256) void k_scores(
    const float* __restrict__ c0, const float* __restrict__ c1,
    const float* __restrict__ c2, const float* __restrict__ c3,
    const float* __restrict__ c4,
    float* __restrict__ scores, unsigned char* __restrict__ classes)
{
    int g4 = blockIdx.x * 256 + threadIdx.x;
    if (g4 >= BATCH * NANCH / 4) return;
    int g = g4 * 4;
    int b = g / NANCH;
    int i = g - b * NANCH;          // multiple of 4; level boundaries are too
    int lvl, h, s, pos;
    levelOf(i, lvl, h, s, pos);
    int hh = h * h;
    const float* cp = (lvl == 0) ? c0 : (lvl == 1) ? c1 : (lvl == 2) ? c2
                      : (lvl == 3) ? c3 : c4;
    const float* base = cp + (size_t)b * NCLS * hh + pos;
    float4 best = make_float4(-1e30f, -1e30f, -1e30f, -1e30f);
    int bcx = 0, bcy = 0, bcz = 0, bcw = 0;
    #pragma unroll
    for (int c = 0; c < NCLS; ++c) {
        float4 v = *(const float4*)(base + (size_t)c * hh);
        float sx = sigmoidf(v.x), sy = sigmoidf(v.y);
        float sz = sigmoidf(v.z), sw = sigmoidf(v.w);
        if (sx > best.x) { best.x = sx; bcx = c; }
        if (sy > best.y) { best.y = sy; bcy = c; }
        if (sz > best.z) { best.z = sz; bcz = c; }
        if (sw > best.w) { best.w = sw; bcw = c; }
    }
    *(float4*)(scores + g) = best;
    *(uchar4*)(classes + g) = make_uchar4(
        (unsigned char)(bcx + 1), (unsigned char)(bcy + 1),
        (unsigned char)(bcz + 1), (unsigned char)(bcw + 1));
}

// ---- Kernel 2: per-batch histogram + threshold (hierarchical wave scan) ---------
__global__ __launch_bounds__(1024) void k_histT(
    const float* __restrict__ scores, int* __restrict__ tbin, int* __restrict__ tcnt)
{
    const int b   = blockIdx.x;
    const int tid = threadIdx.x;
    __shared__ unsigned int lhA[NBIN / 2];   // 64 KB packed u16
    __shared__ unsigned int lhB[NBIN / 2];   // 64 KB packed u16
    __shared__ unsigned int ssuf[1024];
    __shared__ unsigned int wtot[16], winc[16];
    __shared__ int s_c, s_T;

    for (int i = tid; i < NBIN / 2; i += 1024) { lhA[i] = 0u; lhB[i] = 0u; }
    if (tid == 0) { s_c = 0; s_T = 0; tcnt[b * 16] = 0; }
    __syncthreads();

    unsigned int* lh = (tid & 64) ? lhB : lhA;   // wave-parity split
    const float4* sv = (const float4*)(scores + (size_t)b * NANCH);
    for (int f4 = tid; f4 < NANCH / 4; f4 += 1024) {
        float4 v = sv[f4];
        unsigned int bin;
        bin = __float_as_uint(v.x) >> BSHIFT;
        atomicAdd(&lh[bin >> 1], 1u << ((bin & 1) << 4));
        bin = __float_as_uint(v.y) >> BSHIFT;
        atomicAdd(&lh[bin >> 1], 1u << ((bin & 1) << 4));
        bin = __float_as_uint(v.z) >> BSHIFT;
        atomicAdd(&lh[bin >> 1], 1u << ((bin & 1) << 4));
        bin = __float_as_uint(v.w) >> BSHIFT;
        atomicAdd(&lh[bin >> 1], 1u << ((bin & 1) << 4));
    }
    __syncthreads();

    // chunk sum: thread owns bins [32t, 32t+32) = words [16t,16t+16) of A+B
    unsigned int s = 0;
    #pragma unroll
    for (int k = 0; k < 16; ++k) {
        unsigned int wA = lhA[tid * 16 + k];
        unsigned int wB = lhB[tid * 16 + k];
        s += (wA & 0xFFFFu) + (wA >> 16) + (wB & 0xFFFFu) + (wB >> 16);
    }

    // hierarchical suffix scan: per-wave shfl scan + 16 wave-totals
    const int lane = tid & 63, wv = tid >> 6;
    unsigned int suf = s;
    #pragma unroll
    for (int d = 1; d < 64; d <<= 1) {
        unsigned int o = __shfl_down(suf, d);
        if (lane + d < 64) suf += o;
    }
    if (lane == 0) wtot[wv] = suf;
    __syncthreads();
    if (tid < 16) {
        unsigned int sw = wtot[tid];
        #pragma unroll
        for (int d = 1; d < 16; d <<= 1) {
            unsigned int o = __shfl_down(sw, d);
            if (tid + d < 16) sw += o;
        }
        winc[tid] = sw;                      // inclusive wave-suffix
    }
    __syncthreads();
    unsigned int myssuf = suf + ((wv < 15) ? winc[wv + 1] : 0u);
    ssuf[tid] = myssuf;
    __syncthreads();
    if (myssuf >= (unsigned)KTOP &&
        (tid == 1023 || ssuf[tid + 1] < (unsigned)KTOP))
        s_c = tid;
    __syncthreads();
    const int c = s_c;
    const unsigned int hi = (c < 1023) ? ssuf[c + 1] : 0u;

    // fine scan within chunk c (32 bins, one wave)
    if (tid < 64) {
        unsigned int bc = 0;
        if (tid < 32) {
            int bin = c * 32 + tid;
            int sh = (bin & 1) << 4;
            bc = ((lhA[bin >> 1] >> sh) & 0xFFFFu) + ((lhB[bin >> 1] >> sh) & 0xFFFFu);
        }
        unsigned int sf = bc;
        #pragma unroll
        for (int d = 1; d < 32; d <<= 1) {
            unsigned int o = __shfl_down(sf, d);
            if (tid + d < 32) sf += o;
        }
        unsigned int nxt = __shfl_down(sf, 1);
        if (tid < 32) {
            if (hi + sf >= (unsigned)KTOP &&
                (tid == 31 || hi + nxt < (unsigned)KTOP))
                s_T = c * 32 + tid;
        }
    }
    __syncthreads();
    if (tid == 0) tbin[b] = s_T;
}

// ---- Kernel 3: compact candidates — block-aggregated, padded counters -----------
__global__ __launch_bounds__(256) void k_compact(
    const float* __restrict__ scores, const int* __restrict__ tbin,
    int* __restrict__ cnt, unsigned long long* __restrict__ cand)
{
    const int b = blockIdx.y;
    const int t4 = blockIdx.x * 256 + threadIdx.x;   // float4 index within batch
    __shared__ int lcnt;
    __shared__ int lbase;
    if (threadIdx.x == 0) lcnt = 0;
    __syncthreads();

    const int T = tbin[b];
    const bool in = (t4 < NANCH / 4);
    float4 v = make_float4(0.f, 0.f, 0.f, 0.f);
    if (in) v = *(const float4*)(scores + (size_t)b * NANCH + 4 * (size_t)t4);
    unsigned int bits[4] = { __float_as_uint(v.x), __float_as_uint(v.y),
                             __float_as_uint(v.z), __float_as_uint(v.w) };
    int rank[4];
    #pragma unroll
    for (int k = 0; k < 4; ++k) {
        bool pass = in && ((int)(bits[k] >> BSHIFT) >= T);
        rank[k] = pass ? atomicAdd(&lcnt, 1) : -1;
    }
    __syncthreads();
    if (threadIdx.x == 0) lbase = atomicAdd(&cnt[b * 16], lcnt);
    __syncthreads();
    const int base = lbase;
    #pragma unroll
    for (int k = 0; k < 4; ++k) {
        if (rank[k] >= 0) {
            int p = base + rank[k];
            if (p < CAND) {
                unsigned int idx = 4u * (unsigned int)t4 + (unsigned int)k;
                cand[(size_t)b * CAND + p] =
                    ((unsigned long long)bits[k] << 32) |
                    (unsigned long long)(0xFFFFFFFFu - idx);
            }
        }
    }
}

// ---- Kernel 4: exact rank-scatter + lean decode (LDS-staged, n-bounded loop) ----
__global__ __launch_bounds__(256) void k_rankdec(
    const unsigned long long* __restrict__ cand, const int* __restrict__ cnt,
    const float* __restrict__ r0, const float* __restrict__ r1,
    const float* __restrict__ r2, const float* __restrict__ r3,
    const float* __restrict__ r4,
    const unsigned char* __restrict__ classes_all,
    float* __restrict__ tsc, int* __restrict__ tix,
    float* __restrict__ boxes, int* __restrict__ clstop)
{
    const int b  = blockIdx.y;
    const int ci = blockIdx.x * 256 + threadIdx.x;   // 0..2047
    __shared__ unsigned long long keys[CAND];

    const int n = min(cnt[b * 16], CAND);
    for (int i = threadIdx.x; i < n; i += 256)
        keys[i] = cand[(size_t)b * CAND + i];
    __syncthreads();

    if (ci >= n) return;
    const unsigned long long my = keys[ci];

    int rank = 0;
    #pragma unroll 4
    for (int j = 0; j < n; ++j)                      // wave-uniform j -> broadcast
        rank += (keys[j] > my) ? 1 : 0;
    if (rank >= KTOP) return;

    const int g   = b * KTOP + rank;
    const int idx = (int)(0xFFFFFFFFu - (unsigned int)(my & 0xFFFFFFFFull));
    tsc[g] = __uint_as_float((unsigned int)(my >> 32));
    tix[g] = idx;
    clstop[g] = (int)classes_all[(size_t)b * NANCH + idx];

    int lvl, h, s, pos;
    levelOf(idx, lvl, h, s, pos);
    int y = pos / h, x = pos - y * h;
    int hh = h * h;
    const float* rp = (lvl == 0) ? r0 : (lvl == 1) ? r1 : (lvl == 2) ? r2
                      : (lvl == 3) ? r3 : r4;
    const float* rb = rp + (size_t)b * 5 * hh + pos;
    float fs = (float)s;
    float rr0 = rb[0] * fs;
    float rr1 = rb[(size_t)hh] * fs;
    float rr2 = rb[(size_t)2 * hh] * fs;
    float rr3 = rb[(size_t)3 * hh] * fs;
    float cx = (float)(x * s + (s >> 1));
    float cy = (float)(y * s + (s >> 1));
    float* op = boxes + (size_t)g * 5;
    op[0] = cx - rr0;
    op[1] = cy - rr1;
    op[2] = cx + rr2;
    op[3] = cy + rr3;
    // op[4] (theta) written by the theta role of k_masktheta
}

// ---- Kernel 5: FUSED mask + theta. blockIdx.y < 16 -> mask slice; else theta
// slice with TWO anchors per wave (32-lane groups; NTH=18 <= 32). ----------------
__global__ __launch_bounds__(256) void k_masktheta(
    const float* __restrict__ boxes_in, unsigned long long* __restrict__ mask,
    const float* __restrict__ t0, const float* __restrict__ t1,
    const float* __restrict__ t2, const float* __restrict__ t3,
    const float* __restrict__ t4,
    const float* __restrict__ q0, const float* __restrict__ q1,
    const float* __restrict__ q2, const float* __restrict__ q3,
    const float* __restrict__ q4,
    const int* __restrict__ tix, float* __restrict__ boxes_theta)
{
    const int b = blockIdx.x;
    const int role = blockIdx.y;

    if (role < 16) {
        const int by = role;
        __shared__ float bx1[1024], by1[1024], bx2[1024], by2[1024], bar[1024];
        for (int r = threadIdx.x; r < 1024; r += 256) {
            float x1 = 0.f, y1 = 0.f, x2 = 0.f, y2 = 0.f;
            if (r < KTOP) {
                const float* p = boxes_in + ((size_t)(b * KTOP + r)) * 5;
                x1 = p[0]; y1 = p[1]; x2 = p[2]; y2 = p[3];
            }
            bx1[r] = x1; by1[r] = y1; bx2[r] = x2; by2[r] = y2;
            bar[r] = fmaxf(x2 - x1, 0.0f) * fmaxf(y2 - y1, 0.0f);
        }
        __syncthreads();

        const int l  = threadIdx.x & 63;
        const int wv = threadIdx.x >> 6;
        const int i  = (by << 6) + l;
        const float x1 = bx1[i], y1 = by1[i], x2 = bx2[i], y2 = by2[i], ai = bar[i];

        for (int w = by + wv; w < NWORDS; w += 4) {
            const int j0 = w << 6;
            unsigned long long m = 0ull;
            #pragma unroll 8
            for (int jj = 0; jj < 64; ++jj) {
                const int j = j0 + jj;
                float iw = fminf(x2, bx2[j]) - fmaxf(x1, bx1[j]);
                iw = fmaxf(iw, 0.0f);
                float ih = fminf(y2, by2[j]) - fmaxf(y1, by1[j]);
                ih = fmaxf(ih, 0.0f);
                float inter = iw * ih;
                float u = ai + bar[j] - inter;
                float iou = inter / fmaxf(u, 1e-8f);
                unsigned long long bit = (iou > 0.3f && j > i) ? 1ull : 0ull;
                m |= bit << jj;
            }
            mask[(((size_t)b * 1024 + i) << 4) + w] = m;
        }
    } else {
        // theta: 2 anchors per wave -> 8 anchors per 256-thread block
        const int lane = threadIdx.x & 63;
        const int wv   = threadIdx.x >> 6;
        const int grp  = lane >> 5;                  // 0 or 1
        const int gl   = lane & 31;
        int r = (role - 16) * 8 + wv * 2 + grp;      // 0..999
        if (r >= KTOP) return;
        int wid = b * KTOP + r;
        int idx = tix[wid];                          // group-uniform

        int lvl, h, s, pos;
        levelOf(idx, lvl, h, s, pos);
        int hh = h * h;
        const float* tp = (lvl == 0) ? t0 : (lvl == 1) ? t1 : (lvl == 2) ? t2
                          : (lvl == 3) ? t3 : t4;
        const float* qp = (lvl == 0) ? q0 : (lvl == 1) ? q1 : (lvl == 2) ? q2
                          : (lvl == 3) ? q3 : q4;

        float v = -1e30f;
        if (gl < NTH)
            v = sigmoidf(tp[(size_t)b * NTH * hh + pos + (size_t)gl * hh]);
        float m = v;
        m = fmaxf(m, __shfl_xor(m, 1));
        m = fmaxf(m, __shfl_xor(m, 2));
        m = fmaxf(m, __shfl_xor(m, 4));
        m = fmaxf(m, __shfl_xor(m, 8));
        m = fmaxf(m, __shfl_xor(m, 16));             // max within 32-lane group
        unsigned long long eq = __ballot(v == m);    // 64-bit, both groups
        unsigned int gbits = (grp == 0) ? (unsigned int)(eq & 0xFFFFFFFFull)
                                        : (unsigned int)(eq >> 32);
        int bt = __builtin_ctz(gbits);               // first-index tie-break
        float tr = qp[(size_t)b * hh + pos];
        if (gl == 0)
            boxes_theta[(size_t)wid * 5 + 4] = (float)(bt + 1) * 10.0f + tr;
    }
}

// ---- Kernel 6: greedy NMS — sparse exact chain, prefetched rows, one wave -------
#define LOADROW(R, W) do {                                                          \
    const ulonglong2* rp2 = (const ulonglong2*)(mask +                              \
        (((size_t)b * 1024 + ((W) << 6) + l) << 4));                                \
    _Pragma("unroll")                                                               \
    for (int p = 0; p < 8; ++p) {                                                   \
        ulonglong2 v = rp2[p]; R[2 * p] = v.x; R[2 * p + 1] = v.y;                  \
    }                                                                               \
} while (0)

#define PROC(W, R) do {                                                             \
    const unsigned long long rowword = R[W];                                        \
    unsigned long long zr = __ballot(rowword == 0ull);                              \
    unsigned long long remw = sremv[W];                                             \
    unsigned long long pend = vw[W] & ~remw;                                        \
    unsigned long long keptm = 0ull;                                                \
    while (pend) {                                                                  \
        unsigned long long nzp = pend & ~zr;                                        \
        if (!nzp) { keptm |= pend; break; }                                         \
        int jj = __builtin_ctzll(nzp);                                              \
        unsigned long long low = (1ull << jj); low = (low << 1) - 1ull;             \
        keptm |= pend & low;                                                        \
        remw |= shfl_u64(rowword, jj);                                              \
        pend &= ~low; pend &= ~remw;                                                \
    }                                                                               \
    if (l == 0) skeep[W] = keptm;                                                   \
    if ((keptm >> l) & 1ull) {                                                      \
        _Pragma("unroll")                                                           \
        for (int w2 = (W) + 1; w2 < NWORDS; ++w2)                                   \
            if (R[w2]) atomicOr64Shared(&sremv[w2], R[w2]);                         \
    }                                                                               \
} while (0)

__global__ __launch_bounds__(64) void k_nms(
    const unsigned long long* __restrict__ mask,   // [b][1024][16]
    const float* __restrict__ tsc, const int* __restrict__ clstop,
    const float* __restrict__ boxes, float* __restrict__ out)
{
    const int b = blockIdx.x;
    const int l = threadIdx.x;
    __shared__ unsigned long long sremv[NWORDS];
    __shared__ unsigned long long skeep[NWORDS];

    if (l < NWORDS) sremv[l] = 0ull;   // single wave: in-order LDS, no barrier

    unsigned long long vw[NWORDS];
    #pragma unroll
    for (int w = 0; w < NWORDS; ++w) {
        int i = (w << 6) + l;
        bool v = (i < KTOP) && (tsc[b * KTOP + i] >= 0.05f);
        vw[w] = __ballot(v);
    }

    unsigned long long rowA[NWORDS], rowB[NWORDS];
    LOADROW(rowA, 0);
    LOADROW(rowB, 1);   PROC(0, rowA);
    LOADROW(rowA, 2);   PROC(1, rowB);
    LOADROW(rowB, 3);   PROC(2, rowA);
    LOADROW(rowA, 4);   PROC(3, rowB);
    LOADROW(rowB, 5);   PROC(4, rowA);
    LOADROW(rowA, 6);   PROC(5, rowB);
    LOADROW(rowB, 7);   PROC(6, rowA);
    LOADROW(rowA, 8);   PROC(7, rowB);
    LOADROW(rowB, 9);   PROC(8, rowA);
    LOADROW(rowA, 10);  PROC(9, rowB);
    LOADROW(rowB, 11);  PROC(10, rowA);
    LOADROW(rowA, 12);  PROC(11, rowB);
    LOADROW(rowB, 13);  PROC(12, rowA);
    LOADROW(rowA, 14);  PROC(13, rowB);
    LOADROW(rowB, 15);  PROC(14, rowA);
    PROC(15, rowB);

    // fused masked output write
    #pragma unroll
    for (int w = 0; w < NWORDS; ++w) {
        int i = (w << 6) + l;
        if (i < KTOP) {
            int g = b * KTOP + i;
            float fk = (float)((skeep[w] >> l) & 1ull);
            out[g] = tsc[g] * fk;
            out[BATCH * KTOP + g] = (float)clstop[g] * fk;
            const float* bp = boxes + (size_t)g * 5;
            float* op = out + 2 * BATCH * KTOP + (size_t)g * 5;
            op[0] = bp[0] * fk;
            op[1] = bp[1] * fk;
            op[2] = bp[2] * fk;
            op[3] = bp[3] * fk;
            op[4] = bp[4] * fk;
        }
    }
}

extern "C" void kernel_launch(void* const* d_in, const int* in_sizes, int n_in,
                              void* d_out, int out_size, void* d_ws, size_t ws_size,
                              hipStream_t stream) {
    const float* c0 = (const float*)d_in[0];
    const float* c1 = (const float*)d_in[1];
    const float* c2 = (const float*)d_in[2];
    const float* c3 = (const float*)d_in[3];
    const float* c4 = (const float*)d_in[4];
    const float* r0 = (const float*)d_in[5];
    const float* r1 = (const float*)d_in[6];
    const float* r2 = (const float*)d_in[7];
    const float* r3 = (const float*)d_in[8];
    const float* r4 = (const float*)d_in[9];
    const float* t0 = (const float*)d_in[10];
    const float* t1 = (const float*)d_in[11];
    const float* t2 = (const float*)d_in[12];
    const float* t3 = (const float*)d_in[13];
    const float* t4 = (const float*)d_in[14];
    const float* q0 = (const float*)d_in[15];
    const float* q1 = (const float*)d_in[16];
    const float* q2 = (const float*)d_in[17];
    const float* q3 = (const float*)d_in[18];
    const float* q4 = (const float*)d_in[19];

    // Workspace layout, total 6,800,704 B. No aliasing, no zero pass:
    // hist lives in k_histT's LDS; tcnt zeroed by k_histT before k_compact.
    char* ws = (char*)d_ws;
    float*              scores  = (float*)(ws + 0);               // 3,142,656
    unsigned char*      classes = (unsigned char*)(ws + 3142656); //   785,664
    int*                tcnt    = (int*)(ws + 3928320);           //     1,024
    int*                tbin    = (int*)(ws + 3929344);           //        64
    unsigned long long* cand    = (unsigned long long*)(ws + 3929408); // 262,144
    float*              tsc     = (float*)(ws + 4191552);         //    64,000
    int*                tix     = (int*)(ws + 4255552);           //    64,000
    int*                clstop  = (int*)(ws + 4319552);           //    64,000
    float*              boxes   = (float*)(ws + 4383552);         //   320,000
    unsigned long long* mask    = (unsigned long long*)(ws + 4703552); // 2,097,152
    float*              out     = (float*)d_out;

    k_scores<<<(BATCH * NANCH / 4 + 255) / 256, 256, 0, stream>>>(
        c0, c1, c2, c3, c4, scores, classes);
    k_histT<<<BATCH, 1024, 0, stream>>>(scores, tbin, tcnt);
    k_compact<<<dim3(48, BATCH), 256, 0, stream>>>(scores, tbin, tcnt, cand);
    k_rankdec<<<dim3(8, BATCH), 256, 0, stream>>>(
        cand, tcnt, r0, r1, r2, r3, r4, classes, tsc, tix, boxes, clstop);
    k_masktheta<<<dim3(BATCH, 16 + (KTOP + 7) / 8), 256, 0, stream>>>(
        boxes, mask, t0, t1, t2, t3, t4, q0, q1, q2, q3, q4, tix, boxes);
    k_nms<<<BATCH, 64, 0, stream>>>(mask, tsc, clstop, boxes, out);
}